// Round 21
// baseline (859.539 us; speedup 1.0000x reference)
//
#include <hip/hip_runtime.h>
#include <cstdint>
#include <cstddef>

#define N_NEU 2048
#define D_IN  1024
#define T_STEPS 64

typedef _Float16 f16x8 __attribute__((ext_vector_type(8)));
typedef _Float16 f16x4 __attribute__((ext_vector_type(4)));
typedef float    f32x4 __attribute__((ext_vector_type(4)));
typedef unsigned u32x4 __attribute__((ext_vector_type(4)));

#define MFMA16(a, b, c) __builtin_amdgcn_mfma_f32_16x16x32_f16((a), (b), (c), 0, 0, 0)

// ---------------- ws layout (bytes) ----------------
// Wh   [2048][2048] f16   @ 0       (8 MB)
// Wl   [2048][2048] f16   @ 8 MB    (8 MB)
// Iext [256][2048]  f32   @ 16 MB   (2 MB)
// bmv  u32[2][256][128]   @ 18 MB   (256 KB)  (tag<<16)|bits16: word (row, n/16), bit n%16

// 8 bits -> 8 f16 (one/0) via multiply-spread; one=0x3C00 (1.0) or 0x0C00 (2^-12).
__device__ inline f16x8 expand8v(unsigned b, unsigned one) {
  u32x4 t;
#pragma unroll
  for (int i = 0; i < 4; ++i) {
    unsigned m = (b >> (2 * i)) & 3u;
    unsigned s = (m | (m << 15)) & 0x00010001u;
    t[i] = s * one;
  }
  return __builtin_bit_cast(f16x8, t);
}

// Split W_eff = adj*mask into f16 hi + f16 lo' (w ~= hi + lo'/4096). Zeroes bmv (replay!).
__global__ __launch_bounds__(256) void k_wsplit(const float* __restrict__ adj,
                                                const float* __restrict__ mask,
                                                _Float16* __restrict__ Wh,
                                                _Float16* __restrict__ Wl,
                                                unsigned* __restrict__ bmv) {
  const int idx = blockIdx.x * 256 + threadIdx.x;
  if (idx < 2 * 256 * 128) bmv[idx] = 0u;
  const int total4 = (N_NEU * N_NEU) / 4;
  for (int i = idx; i < total4; i += gridDim.x * 256) {
    float4 a = ((const float4*)adj)[i];
    float4 m = ((const float4*)mask)[i];
    float w0 = a.x * m.x, w1 = a.y * m.y, w2 = a.z * m.z, w3 = a.w * m.w;
    f16x4 h, lo;
    h[0] = (_Float16)w0; lo[0] = (_Float16)((w0 - (float)h[0]) * 4096.0f);
    h[1] = (_Float16)w1; lo[1] = (_Float16)((w1 - (float)h[1]) * 4096.0f);
    h[2] = (_Float16)w2; lo[2] = (_Float16)((w2 - (float)h[2]) * 4096.0f);
    h[3] = (_Float16)w3; lo[3] = (_Float16)((w3 - (float)h[3]) * 4096.0f);
    ((f16x4*)Wh)[i] = h;
    ((f16x4*)Wl)[i] = lo;
  }
}

// I_ext = ext @ W_in^T + b_in, plain fp32. Proven absmax 0.0 (r1/r5-r20).
__global__ __launch_bounds__(256) void k_iext(const float* __restrict__ ext,
                                              const float* __restrict__ Win,
                                              const float* __restrict__ bin,
                                              float* __restrict__ Iext) {
  __shared__ float At[32][68];
  __shared__ float Bt[32][68];
  const int tid = threadIdx.x;
  const int b0 = (blockIdx.x & 3) * 64;
  const int n0 = (blockIdx.x >> 2) * 64;
  const int tx = tid & 15, ty = tid >> 4;
  float acc[4][4] = {};
  for (int kt = 0; kt < D_IN / 32; ++kt) {
    const int k0 = kt * 32;
#pragma unroll
    for (int i = 0; i < 8; ++i) {
      int e = tid + i * 256;
      int kk = e & 31, row = e >> 5;
      At[kk][row] = ext[(size_t)(b0 + row) * D_IN + k0 + kk];
      Bt[kk][row] = Win[(size_t)(n0 + row) * D_IN + k0 + kk];
    }
    __syncthreads();
    for (int kk = 0; kk < 32; ++kk) {
      f32x4 a = *(const f32x4*)&At[kk][ty * 4];
      f32x4 b = *(const f32x4*)&Bt[kk][tx * 4];
#pragma unroll
      for (int i = 0; i < 4; ++i)
#pragma unroll
        for (int j = 0; j < 4; ++j) acc[i][j] += a[i] * b[j];
    }
    __syncthreads();
  }
#pragma unroll
  for (int i = 0; i < 4; ++i)
#pragma unroll
    for (int j = 0; j < 4; ++j)
      Iext[(size_t)(b0 + ty * 4 + i) * N_NEU + n0 + tx * 4 + j] = acc[i][j] + bin[n0 + tx * 4 + j];
}

// Persistent fused LIF kernel: 16-col tiles, FULL W residency in VGPRs.
// 256 blocks x 256 thr (4 waves = 1 wave/SIMD -> 256-VGPR cap). Block (rg 0..1, ns 0..127):
// rows rg*128..+128 (two groups of 64), cols ns*16..+16. Wave kw 0..3 owns K-slice 512:
// W frags = 128 VGPRs. Merged hi/lo MFMA chain (lo A-operand pre-scaled 2^-12).
// Zero-barrier dataflow with 16-bit tagged spike words.
__global__ __launch_bounds__(256, 1) void k_fused18(
    const _Float16* __restrict__ Wh, const _Float16* __restrict__ Wl,
    const float* __restrict__ Iext, unsigned* __restrict__ bmv,
    float* __restrict__ out) {
  __shared__ unsigned bm[2][64 * 64];   // 2 x 16 KB: packed spike bytes [row][pw ^ swz]
  __shared__ float red[2][4 * 16 * 68]; // 2 x 17 KB: [wave][col][row 64+4pad]

  const int tid = threadIdx.x;
  const int lane = tid & 63;
  const int kw = tid >> 6;        // wave id = split-K index 0..3 (512 K each)
  const int l15 = lane & 15;
  const int klo = lane >> 4;      // 0..3
  const int rg = blockIdx.x >> 7; // 0..1
  const int ns = blockIdx.x & 127;
  const int n0 = ns * 16;
  const int rowbase = rg * 128;

  // ---------- resident W fragments: whf+wlf = 128 VGPRs ----------
  // k = kw*512 + kcl*32 + klo*8 + reg; B frag col = l15.
  const _Float16* whb = Wh + (size_t)(n0 + l15) * N_NEU + kw * 512 + klo * 8;
  const _Float16* wlb = Wl + (size_t)(n0 + l15) * N_NEU + kw * 512 + klo * 8;
  f16x8 whf[16], wlf[16];
#pragma unroll
  for (int kcl = 0; kcl < 16; ++kcl) {
    whf[kcl] = *(const f16x8*)(whb + kcl * 32);
    wlf[kcl] = *(const f16x8*)(wlb + kcl * 32);
  }

  // ---------- per-thread Iext: 4 rows per group (row = base+kw*16+klo*4+j, col l15) ----------
  float IxA[4], IxB[4];
#pragma unroll
  for (int j = 0; j < 4; ++j) {
    IxA[j] = Iext[(size_t)(rowbase + kw * 16 + klo * 4 + j) * N_NEU + n0 + l15];
    IxB[j] = Iext[(size_t)(rowbase + 64 + kw * 16 + klo * 4 + j) * N_NEU + n0 + l15];
  }

  float VA[4] = {0.f, 0.f, 0.f, 0.f}, VB[4] = {0.f, 0.f, 0.f, 0.f};
  unsigned cA[4] = {0u, 0u, 0u, 0u}, cB[4] = {0u, 0u, 0u, 0u};
  unsigned long long vA[16], vB[16];

  // speculative coalesced load of group g's slab (64 rows x 128 tagged u32 = 32 KB)
  auto spec_issue = [&](int g, int buf, unsigned long long (&v)[16]) {
    const unsigned long long* src =
        (const unsigned long long*)(bmv + (size_t)buf * 32768 + (size_t)(rowbase + g * 64) * 128) + tid;
#pragma unroll
    for (int i = 0; i < 16; ++i)
      v[i] = __hip_atomic_load(src + (size_t)i * 256, __ATOMIC_RELAXED, __HIP_MEMORY_SCOPE_AGENT);
  };
  // validate both 16-bit tags per u64; retry stale
  auto check_retry = [&](int g, int buf, unsigned want, unsigned long long (&v)[16]) {
    const unsigned long long* src =
        (const unsigned long long*)(bmv + (size_t)buf * 32768 + (size_t)(rowbase + g * 64) * 128) + tid;
    unsigned need = 0u;
#pragma unroll
    for (int i = 0; i < 16; ++i) {
      const unsigned lo = (unsigned)v[i], hi = (unsigned)(v[i] >> 32);
      if ((lo >> 16) != want || (hi >> 16) != want) need |= 1u << i;
    }
    while (need) {
      __builtin_amdgcn_s_sleep(1);
#pragma unroll
      for (int i = 0; i < 16; ++i)
        if (need & (1u << i)) {
          v[i] = __hip_atomic_load(src + (size_t)i * 256,
                                   __ATOMIC_RELAXED, __HIP_MEMORY_SCOPE_AGENT);
          const unsigned lo = (unsigned)v[i], hi = (unsigned)(v[i] >> 32);
          if ((lo >> 16) == want && (hi >> 16) == want) need &= ~(1u << i);
        }
    }
  };
  // stage: strip tags, pack 2x16-bit payloads -> 1 u32 (natural byte order), swizzled write
  auto stage = [&](unsigned* bmg, const unsigned long long (&v)[16]) {
#pragma unroll
    for (int i = 0; i < 16; ++i) {
      const int m = i * 256 + tid;          // u64-pair index 0..4095
      const int r = m >> 6, pw = m & 63;    // row 0..63, packed word 0..63
      const unsigned packed = ((unsigned)v[i] & 0xFFFFu) | (((unsigned)(v[i] >> 32) & 0xFFFFu) << 16);
      bmg[r * 64 + (pw ^ ((r & 15) << 2))] = packed;
    }
  };
  // gemm: 4 rowtiles x 16 kcl x {hi,lo} MFMA (merged chain) + 4-slab reduce -> cI (f32x4)
  auto gemm = [&](const unsigned* bmg, float* redp, f32x4& cI) {
    const f32x4 z4 = {0.f, 0.f, 0.f, 0.f};
    f32x4 acc0 = z4, acc1 = z4, acc2 = z4, acc3 = z4;
    __builtin_amdgcn_s_setprio(1);
#pragma unroll
    for (int rt = 0; rt < 4; ++rt) {
      const int row = rt * 16 + l15;
      const int sw = (row & 15) << 2;
      u32x4 q[4];
#pragma unroll
      for (int jj = 0; jj < 4; ++jj)
        q[jj] = *(const u32x4*)&bmg[row * 64 + ((kw * 16 + jj * 4) ^ sw)];
      f32x4* accp = (rt == 0) ? &acc0 : (rt == 1) ? &acc1 : (rt == 2) ? &acc2 : &acc3;
      f32x4 a_ = *accp;
#pragma unroll
      for (int kcl = 0; kcl < 16; ++kcl) {
        const unsigned byte = (q[kcl >> 2][kcl & 3] >> (klo * 8)) & 0xFFu;
        a_ = MFMA16(expand8v(byte, 0x3C00u), whf[kcl], a_);
        a_ = MFMA16(expand8v(byte, 0x0C00u), wlf[kcl], a_);
      }
      *accp = a_;
    }
    __builtin_amdgcn_s_setprio(0);
    // store: red[kw][col=l15][rt*16 + klo*4 .. +3]
    float* rb = redp + (size_t)(kw * 16 + l15) * 68;
    *(f32x4*)&rb[0 * 16 + klo * 4] = acc0;
    *(f32x4*)&rb[1 * 16 + klo * 4] = acc1;
    *(f32x4*)&rb[2 * 16 + klo * 4] = acc2;
    *(f32x4*)&rb[3 * 16 + klo * 4] = acc3;
    __syncthreads();
    // sum 4 slabs: thread's rows kw*16 + klo*4 .. +3, col l15
    f32x4 s = *(const f32x4*)&redp[(size_t)(0 * 16 + l15) * 68 + kw * 16 + klo * 4];
#pragma unroll
    for (int w = 1; w < 4; ++w)
      s += *(const f32x4*)&redp[(size_t)(w * 16 + l15) * 68 + kw * 16 + klo * 4];
    cI = s;
  };
  // LIF + tagged 16-bit spike stores (ballot fields: 4 rows per wave per round)
  auto lif = [&](const f32x4& cI, const float (&Ix)[4], float (&V)[4],
                 unsigned (&cnt)[4], int g, int nbuf, unsigned tag, bool dostore) {
#pragma unroll
    for (int j = 0; j < 4; ++j) {
      float I = cI[j] + Ix[j];
      float v = 0.9f * V[j] + I;
      bool sp = (v - 1.0f) >= 0.0f;
      V[j] = sp ? 0.0f : v;
      cnt[j] += sp ? 1u : 0u;
      if (dostore) {
        unsigned long long ba = __ballot(sp);
        if (l15 == 0) {
          const int R = rowbase + g * 64 + kw * 16 + klo * 4 + j;
          const unsigned val = (tag << 16) | ((unsigned)(ba >> (klo * 16)) & 0xFFFFu);
          __hip_atomic_store(bmv + (size_t)nbuf * 32768 + (size_t)R * 128 + ns, val,
                             __ATOMIC_RELAXED, __HIP_MEMORY_SCOPE_AGENT);
        }
      }
    }
  };

  // ---------- t = 0: Iext-only LIF; spikes tagged 1 -> buf 1; prefetch A ----------
  {
    const f32x4 z4 = {0.f, 0.f, 0.f, 0.f};
    lif(z4, IxA, VA, cA, 0, 1, 1u, true);
    lif(z4, IxB, VB, cB, 1, 1, 1u, true);
    spec_issue(0, 1, vA);
  }

  for (int t = 1; t < T_STEPS; ++t) {
    const int cbuf = t & 1, nbuf = (t + 1) & 1;
    const bool last = (t == T_STEPS - 1);
    f32x4 cI;

    // ---- phase A (rows rowbase..+64) ----
    check_retry(0, cbuf, (unsigned)t, vA);
    stage(bm[0], vA);
    __syncthreads();
    spec_issue(1, cbuf, vB);             // in flight under gemm(A)
    gemm(bm[0], red[0], cI);
    lif(cI, IxA, VA, cA, 0, nbuf, (unsigned)(t + 1), !last);

    // ---- phase B (rows rowbase+64..+128) ----
    check_retry(1, cbuf, (unsigned)t, vB);
    stage(bm[1], vB);
    __syncthreads();
    if (!last) spec_issue(0, nbuf, vA);  // in flight under gemm(B)
    gemm(bm[1], red[1], cI);
    lif(cI, IxB, VB, cB, 1, nbuf, (unsigned)(t + 1), !last);
  }

  // ---------- write firing rates ----------
#pragma unroll
  for (int j = 0; j < 4; ++j) {
    const int rA = rowbase + kw * 16 + klo * 4 + j;
    const int rB = rA + 64;
    out[(size_t)rA * N_NEU + n0 + l15] = (float)cA[j] * 0.015625f;
    out[(size_t)rB * N_NEU + n0 + l15] = (float)cB[j] * 0.015625f;
  }
}

extern "C" void kernel_launch(void* const* d_in, const int* in_sizes, int n_in,
                              void* d_out, int out_size, void* d_ws, size_t ws_size,
                              hipStream_t stream) {
  (void)in_sizes; (void)n_in; (void)out_size; (void)ws_size;
  const float* ext  = (const float*)d_in[0];
  const float* Win  = (const float*)d_in[1];
  const float* bin  = (const float*)d_in[2];
  const float* adj  = (const float*)d_in[3];
  const float* mask = (const float*)d_in[4];
  unsigned char* ws = (unsigned char*)d_ws;

  _Float16* Wh   = (_Float16*)(ws);
  _Float16* Wl   = (_Float16*)(ws + (size_t)(8u << 20));
  float*    Iext = (float*)   (ws + (size_t)(16u << 20));
  unsigned* bmv  = (unsigned*)(ws + (size_t)(18u << 20));
  float* out = (float*)d_out;

  hipLaunchKernelGGL(k_wsplit, dim3(2048), dim3(256), 0, stream, adj, mask, Wh, Wl, bmv);
  hipLaunchKernelGGL(k_iext,   dim3(128),  dim3(256), 0, stream, ext, Win, bin, Iext);
  hipLaunchKernelGGL(k_fused18, dim3(256), dim3(256), 0, stream,
                     Wh, Wl, Iext, bmv, out);
}